// Round 12
// baseline (48.180 us; speedup 1.0000x reference)
//
#include <hip/hip_runtime.h>

// NovelKQRAttention — algebraically collapsed, 6-kernel chain (R3 structure + ILP).
// energy = a[...,q,None] + b[...,None,k]; softmax over k => a cancels,
// attn = softmax_k(b) independent of q => deform-conv path is dead,
// attention output constant over spatial dims.
//
//   K1 k_bpart  : partial b[n,h,k] per 36-ch chunk (kb-slice inline, FULL-unroll
//                 e-loop => 64 loads in flight), 128 blocks
//   K2 k_softmax: sum 16 chunks (float4) + softmax over k=1024 -> p (18 blocks)
//   K3 k_wx     : wx[n,h,c] = sum_k p[h,k]*x_kv[n,c,k], unroll-16 gather, 288 blk
//   K4 k_ov     : ov[n,o] = value_w[o,:] . wx[n,h(o),:]  (1 wave/out, 288 blk)
//   K5 k_po     : po[n,o] = proj_w[o,:] . ov[n,:] + proj_b (1 wave/out, 288 blk)
//   K6 k_final  : out = gamma*po[n,o] + x  (2048 blocks, float4 grid-stride)

#define CCH 576
#define NH 9
#define HW 4096   // 64*64
#define KHW 1024  // 32*32
#define W 64
#define CHN 16    // channel chunks
#define CPC 36    // channels per chunk

// ws float offsets
#define WS_BPART 0                    // 2*16*9*1024 = 294912  (layout [n][ch][h][k])
#define WS_P     294912               // 2*9*1024    = 18432
#define WS_WX    (294912 + 18432)     // 2*9*576     = 10368
#define WS_OV    (294912 + 18432 + 10368)          // 2*576 = 1152
#define WS_PO    (294912 + 18432 + 10368 + 1152)   // 2*576 = 1152

// grid (4 kblk, 2 n, 16 chunk), block 256.
__global__ void k_bpart(const float* __restrict__ x, const float* __restrict__ key_w,
                        const float* __restrict__ appr_bias, float* __restrict__ bpart) {
    int k  = blockIdx.x * 256 + threadIdx.x;   // 0..1023
    int n  = blockIdx.y;
    int ch = blockIdx.z;
    int c0 = ch * CPC;

    __shared__ float ab[CCH];
    __shared__ float kbs[NH][CPC];
    for (int i = threadIdx.x; i < CCH; i += 256) ab[i] = appr_bias[i];
    __syncthreads();
    for (int t = threadIdx.x; t < NH * CPC; t += 256) {
        int h = t / CPC, cl = t % CPC;
        const float* kwr = key_w + (size_t)(h * 64) * CCH + c0 + cl;
        float s = 0.f;
        #pragma unroll   // FULL unroll: 64 independent loads in flight
        for (int e = 0; e < 64; ++e)
            s += ab[h * 64 + e] * kwr[(size_t)e * CCH];
        kbs[h][cl] = s;
    }
    __syncthreads();

    int ky = k >> 5, kx = k & 31;
    const float* xb = x + (size_t)n * CCH * HW + (size_t)c0 * HW + (size_t)(ky * 2) * W + kx * 2;
    float acc[NH];
    #pragma unroll
    for (int h = 0; h < NH; ++h) acc[h] = 0.f;
    #pragma unroll 12
    for (int cl = 0; cl < CPC; ++cl) {
        float xv = xb[(size_t)cl * HW];
        #pragma unroll
        for (int h = 0; h < NH; ++h) acc[h] += kbs[h][cl] * xv;
    }
    #pragma unroll
    for (int h = 0; h < NH; ++h)
        bpart[(((size_t)n * CHN + ch) * NH + h) * KHW + k] = acc[h];
}

// grid 18 (= n*9), block 256. Sum 16 chunks (float4), softmax over k=1024, write p.
__global__ void k_softmax(const float* __restrict__ bpart, float* __restrict__ p) {
    int nh = blockIdx.x;
    int n = nh / NH, h = nh % NH;
    int tid = threadIdx.x;
    int wave = tid >> 6, lane = tid & 63;
    const float4* bp4 = (const float4*)bpart;

    float4 s = make_float4(0.f, 0.f, 0.f, 0.f);
    #pragma unroll   // 16 independent float4 loads in flight
    for (int ch = 0; ch < CHN; ++ch) {
        float4 b = bp4[(((size_t)n * CHN + ch) * NH + h) * (KHW / 4) + tid];
        s.x += b.x; s.y += b.y; s.z += b.z; s.w += b.w;
    }
    float m = fmaxf(fmaxf(s.x, s.y), fmaxf(s.z, s.w));
    #pragma unroll
    for (int off = 32; off >= 1; off >>= 1)
        m = fmaxf(m, __shfl_xor(m, off, 64));
    __shared__ float redm[4];
    if (lane == 0) redm[wave] = m;
    __syncthreads();
    m = fmaxf(fmaxf(redm[0], redm[1]), fmaxf(redm[2], redm[3]));

    float4 e;
    e.x = __expf(s.x - m); e.y = __expf(s.y - m);
    e.z = __expf(s.z - m); e.w = __expf(s.w - m);
    float lsum = e.x + e.y + e.z + e.w;
    #pragma unroll
    for (int off = 32; off >= 1; off >>= 1)
        lsum += __shfl_xor(lsum, off, 64);
    __shared__ float reds[4];
    if (lane == 0) reds[wave] = lsum;
    __syncthreads();
    float inv = 1.f / (reds[0] + reds[1] + reds[2] + reds[3]);
    e.x *= inv; e.y *= inv; e.z *= inv; e.w *= inv;
    ((float4*)p)[(size_t)nh * (KHW / 4) + tid] = e;
}

// grid (144 c-tiles, 2 n), block 256 (4 waves). Each wave: 1 channel, reduce over k.
__global__ void k_wx(const float* __restrict__ x, const float* __restrict__ p,
                     float* __restrict__ wx) {
    int n = blockIdx.y;
    int tid = threadIdx.x;
    int wv = tid >> 6, ln = tid & 63;
    __shared__ float ps[NH * KHW];  // 36 KB
    const float4* p4 = (const float4*)(p + (size_t)n * NH * KHW);
    float4* ps4 = (float4*)ps;
    for (int i = tid; i < NH * KHW / 4; i += 256) ps4[i] = p4[i];
    __syncthreads();

    int c = blockIdx.x * 4 + wv;
    const float* xb = x + ((size_t)n * CCH + c) * HW;
    float acc[NH];
    #pragma unroll
    for (int h = 0; h < NH; ++h) acc[h] = 0.f;
    #pragma unroll   // FULL unroll: 16 independent gather loads in flight
    for (int j = 0; j < 16; ++j) {
        int k = ln + 64 * j;
        int ky = k >> 5, kx = k & 31;
        float xv = xb[(size_t)(ky * 2) * W + kx * 2];
        #pragma unroll
        for (int h = 0; h < NH; ++h) acc[h] += ps[h * KHW + k] * xv;
    }
    #pragma unroll
    for (int h = 0; h < NH; ++h) {
        float v = acc[h];
        #pragma unroll
        for (int off = 32; off >= 1; off >>= 1) v += __shfl_xor(v, off, 64);
        if (ln == 0) wx[((size_t)n * NH + h) * CCH + c] = v;
    }
}

// one wave per output element; grid 288, block 256 (4 waves)
__global__ void k_ov(const float* __restrict__ value_w, const float* __restrict__ wx,
                     float* __restrict__ ov) {
    int g = blockIdx.x * 4 + (threadIdx.x >> 6);   // 0..1151
    int lane = threadIdx.x & 63;
    int n = g / CCH, o = g % CCH;
    int h = o >> 6;
    const float* vw  = value_w + (size_t)o * CCH;
    const float* wxr = wx + ((size_t)n * NH + h) * CCH;
    float acc = 0.f;
    #pragma unroll
    for (int j = 0; j < 9; ++j)
        acc += vw[lane + 64 * j] * wxr[lane + 64 * j];
    #pragma unroll
    for (int off = 32; off >= 1; off >>= 1)
        acc += __shfl_xor(acc, off, 64);
    if (lane == 0) ov[n * CCH + o] = acc;
}

// one wave per output element; grid 288, block 256 (4 waves)
__global__ void k_po(const float* __restrict__ proj_w, const float* __restrict__ proj_b,
                     const float* __restrict__ ov, float* __restrict__ po) {
    int g = blockIdx.x * 4 + (threadIdx.x >> 6);
    int lane = threadIdx.x & 63;
    int n = g / CCH, o = g % CCH;
    const float* pw  = proj_w + (size_t)o * CCH;
    const float* ovr = ov + n * CCH;
    float acc = 0.f;
    #pragma unroll
    for (int j = 0; j < 9; ++j)
        acc += pw[lane + 64 * j] * ovr[lane + 64 * j];
    #pragma unroll
    for (int off = 32; off >= 1; off >>= 1)
        acc += __shfl_xor(acc, off, 64);
    if (lane == 0) po[n * CCH + o] = acc + proj_b[o];
}

// out[n,o,:,:] = gamma*po[n,o] + x ; vectorized float4 grid-stride, 2048 blocks
__global__ void k_final(const float* __restrict__ x, const float* __restrict__ po,
                        const float* __restrict__ gamma, float* __restrict__ out) {
    const size_t total4 = (size_t)2 * CCH * HW / 4;   // 1179648
    float g = gamma[0];
    const float4* x4 = (const float4*)x;
    float4* o4 = (float4*)out;
    for (size_t i = (size_t)blockIdx.x * blockDim.x + threadIdx.x; i < total4;
         i += (size_t)gridDim.x * blockDim.x) {
        int no = (int)(i >> 10);            // (i*4)/HW, HW=4096
        float base = g * po[no];
        float4 v = x4[i];
        v.x += base; v.y += base; v.z += base; v.w += base;
        o4[i] = v;
    }
}

extern "C" void kernel_launch(void* const* d_in, const int* in_sizes, int n_in,
                              void* d_out, int out_size, void* d_ws, size_t ws_size,
                              hipStream_t stream) {
    const float* x         = (const float*)d_in[0];
    const float* key_w     = (const float*)d_in[1];
    // d_in[2] offset_w, d_in[3] dconv_w, d_in[8] appr_bias_q: dead path (a cancels in softmax)
    const float* value_w   = (const float*)d_in[4];
    const float* proj_w    = (const float*)d_in[5];
    const float* proj_b    = (const float*)d_in[6];
    const float* appr_bias = (const float*)d_in[7];
    const float* gamma     = (const float*)d_in[9];
    float* out = (float*)d_out;

    float* ws    = (float*)d_ws;
    float* bpart = ws + WS_BPART;
    float* p     = ws + WS_P;
    float* wx    = ws + WS_WX;
    float* ov    = ws + WS_OV;
    float* po    = ws + WS_PO;

    k_bpart  <<<dim3(4, 2, CHN), 256, 0, stream>>>(x, key_w, appr_bias, bpart);
    k_softmax<<<18, 256, 0, stream>>>(bpart, p);
    k_wx     <<<dim3(144, 2), 256, 0, stream>>>(x, p, wx);
    k_ov     <<<288, 256, 0, stream>>>(value_w, wx, ov);
    k_po     <<<288, 256, 0, stream>>>(proj_w, proj_b, ov, po);
    k_final  <<<2048, 256, 0, stream>>>(x, po, gamma, out);
}